// Round 7
// baseline (855.246 us; speedup 1.0000x reference)
//
#include <hip/hip_runtime.h>
#include <hip/hip_bf16.h>

// Problem shapes (fixed by setup_inputs)
#define B_    1024
#define D_    768
#define POOL_ 100
#define PLEN_ 8
#define TOPK_ 3
#define EK_ELEMS (B_ * 4 * D_)           // 3,145,728
#define XB_ELEMS (B_ * 197 * D_)         // 154,976,256
#define XB_F4    (XB_ELEMS / 4)          // 38,744,064 float4s
#define COPY_BLOCKS 8192

// ============ DIAGNOSTIC ROUND ============
// R1..R6 never surfaced our kernels in the top-5 counter rows (harness fills
// at 376-394 us mask everything below). S (score) and C (copy) are only known
// as S + C ~ 360 us. This round: copy runs x2 passes, score runs x4 reps
// (both idempotent) to (a) force both above the visibility cutoff with full
// counters, (b) solve S and C exactly from total_R7 - total_R6.
#define COPY_PASSES 2
#define SCORE_REPS  4

typedef float f4_t __attribute__((ext_vector_type(4)));

// ---------------------------------------------------------------------------
// Kernel 1: per-pool-row prep: sm[k,:] = softmax(A[k,:]) (f64),
//           nK[k,:] = K[k,:] / max(||K[k,:]||, 1e-12)   (f64)
// ---------------------------------------------------------------------------
__global__ void prep_kernel(const float* __restrict__ A, const float* __restrict__ K,
                            double* __restrict__ sm, double* __restrict__ nK) {
    const int k = blockIdx.x;
    const int t = threadIdx.x;
    const int wave = t >> 6, lane = t & 63;
    __shared__ double red[4];

    double m = -1e300;
    for (int d = t; d < D_; d += 256) m = fmax(m, (double)A[k * D_ + d]);
    #pragma unroll
    for (int off = 32; off >= 1; off >>= 1) m = fmax(m, __shfl_xor(m, off));
    if (lane == 0) red[wave] = m;
    __syncthreads();
    m = fmax(fmax(red[0], red[1]), fmax(red[2], red[3]));
    __syncthreads();

    double s = 0.0;
    for (int d = t; d < D_; d += 256) s += exp((double)A[k * D_ + d] - m);
    #pragma unroll
    for (int off = 32; off >= 1; off >>= 1) s += __shfl_xor(s, off);
    if (lane == 0) red[wave] = s;
    __syncthreads();
    s = red[0] + red[1] + red[2] + red[3];
    __syncthreads();

    for (int d = t; d < D_; d += 256)
        sm[k * D_ + d] = exp((double)A[k * D_ + d] - m) / s;

    double ss = 0.0;
    for (int d = t; d < D_; d += 256) {
        double v = (double)K[k * D_ + d];
        ss += v * v;
    }
    #pragma unroll
    for (int off = 32; off >= 1; off >>= 1) ss += __shfl_xor(ss, off);
    if (lane == 0) red[wave] = ss;
    __syncthreads();
    ss = red[0] + red[1] + red[2] + red[3];
    const double n = fmax(sqrt(ss), 1e-12);

    for (int d = t; d < D_; d += 256)
        nK[k * D_ + d] = (double)K[k * D_ + d] / n;
}

// ---------------------------------------------------------------------------
// Kernel 2: score + wave-parallel top-3 + gather, one block per b-row.
// DIAGNOSTIC: whole body repeated SCORE_REPS times (idempotent rewrites of
// the same out locations). No __restrict__ + memory clobber between reps so
// the compiler cannot hoist/skip the recompute.
// ---------------------------------------------------------------------------
__global__ void __launch_bounds__(256)
score_gather_kernel(const float* xq,
                    const double* sm,
                    const double* nK,
                    const float* p,
                    float* out) {
    __shared__ double s_xq[D_];
    __shared__ double s_aq[POOL_];
    __shared__ int    s_idx[TOPK_];
    const int b = blockIdx.x;
    const int t = threadIdx.x;
    const int wave = t >> 6, lane = t & 63;

    for (int rep = 0; rep < SCORE_REPS; ++rep) {
        __syncthreads();
        for (int d = t; d < D_; d += 256) s_xq[d] = (double)xq[b * D_ + d];
        __syncthreads();

        for (int k = wave; k < POOL_; k += 4) {
            const double* smk = sm + (size_t)k * D_;
            const double* nkk = nK + (size_t)k * D_;
            double dot = 0.0, sq = 0.0;
            for (int d = lane; d < D_; d += 64) {
                double v = s_xq[d] * smk[d];
                dot += v * nkk[d];
                sq  += v * v;
            }
            #pragma unroll
            for (int off = 32; off >= 1; off >>= 1) {
                dot += __shfl_xor(dot, off);
                sq  += __shfl_xor(sq, off);
            }
            if (lane == 0) s_aq[k] = dot / fmax(sqrt(sq), 1e-12);
        }
        __syncthreads();

        if (wave == 0) {
            // lane covers k = lane and k = lane+64; tie -> lowest index
            double v0 = (lane < POOL_) ? s_aq[lane] : -1e300;
            double v1 = (lane + 64 < POOL_) ? s_aq[lane + 64] : -1e300;
            #pragma unroll
            for (int r = 0; r < TOPK_; ++r) {
                double v; int ki;
                if (v0 >= v1) { v = v0; ki = lane; }
                else          { v = v1; ki = lane + 64; }
                #pragma unroll
                for (int off = 32; off >= 1; off >>= 1) {
                    double ov = __shfl_xor(v, off);
                    int    oi = __shfl_xor(ki, off);
                    if (ov > v || (ov == v && oi < ki)) { v = ov; ki = oi; }
                }
                if (lane == 0) s_idx[r] = ki;
                if (ki == lane)      v0 = -1e300;
                if (ki == lane + 64) v1 = -1e300;
            }
        }
        __syncthreads();
        const int i0 = s_idx[0], i1 = s_idx[1], i2 = s_idx[2];

        // gather: 8 prompt-rows x 192 float4 = 1536 units over 256 threads
        for (int w = t; w < PLEN_ * 192; w += 256) {
            const int j = w / 192, c = w % 192;
            const f4_t* q0 = (const f4_t*)(p + (size_t)(j * POOL_ + i0) * D_);
            const f4_t* q1 = (const f4_t*)(p + (size_t)(j * POOL_ + i1) * D_);
            const f4_t* q2 = (const f4_t*)(p + (size_t)(j * POOL_ + i2) * D_);
            f4_t v = q0[c] + q1[c] + q2[c];
            float* dst = (j < 4) ? out + ((size_t)b * 4 + j) * D_
                                 : out + EK_ELEMS + ((size_t)b * 4 + (j - 4)) * D_;
            ((f4_t*)dst)[c] = v;
        }
        asm volatile("" ::: "memory");   // force full recompute next rep
    }
}

// ---------------------------------------------------------------------------
// Kernel 3: x_block passthrough, plain grid-stride float4.
// DIAGNOSTIC: COPY_PASSES full passes (pass 2 rewrites identical data).
// No __restrict__ so pass-2 loads can't be folded into pass-1 values.
// ---------------------------------------------------------------------------
__global__ void __launch_bounds__(256)
copy_kernel(const f4_t* src, f4_t* dst) {
    for (int pass = 0; pass < COPY_PASSES; ++pass) {
        size_t i = (size_t)blockIdx.x * 256 + threadIdx.x;
        const size_t stride = (size_t)COPY_BLOCKS * 256;
        for (; i < (size_t)XB_F4; i += stride)
            dst[i] = src[i];
        asm volatile("" ::: "memory");
    }
}

extern "C" void kernel_launch(void* const* d_in, const int* in_sizes, int n_in,
                              void* d_out, int out_size, void* d_ws, size_t ws_size,
                              hipStream_t stream) {
    const float* x_querry = (const float*)d_in[0];   // (1024, 768)
    const float* x_block  = (const float*)d_in[1];   // (1024, 197, 768)
    const float* K        = (const float*)d_in[2];   // (100, 768)
    const float* A        = (const float*)d_in[3];   // (100, 768)
    const float* p        = (const float*)d_in[4];   // (8, 100, 768)
    // d_in[5] = l (unused)

    float* out = (float*)d_out;

    // workspace layout
    double* sm = (double*)d_ws;                 // 100*768 f64 = 614400 B
    double* nK = sm + (size_t)POOL_ * D_;       // 614400 B

    prep_kernel<<<POOL_, 256, 0, stream>>>(A, K, sm, nK);
    score_gather_kernel<<<B_, 256, 0, stream>>>(x_querry, sm, nK, p, out);
    copy_kernel<<<COPY_BLOCKS, 256, 0, stream>>>(
        (const f4_t*)x_block, (f4_t*)(out + 2 * (size_t)EK_ELEMS));
}

// Round 8
// 308.735 us; speedup vs baseline: 2.7702x; 2.7702x over previous
//
#include <hip/hip_runtime.h>
#include <hip/hip_bf16.h>

// Problem shapes (fixed by setup_inputs)
#define B_    1024
#define D_    768
#define POOL_ 100
#define PLEN_ 8
#define TOPK_ 3
#define EK_ELEMS (B_ * 4 * D_)           // 3,145,728
#define XB_ELEMS (B_ * 197 * D_)         // 154,976,256
#define XB_F4    (XB_ELEMS / 4)          // 38,744,064 float4s
#define COPY_BLOCKS 8192                 // proven 6.4 TB/s config (R7 direct)
#define NBLOCKS (B_ + COPY_BLOCKS)       // 1024 score + 8192 copy

typedef float f4_t __attribute__((ext_vector_type(4)));

// ---------------------------------------------------------------------------
// Kernel 1: per-pool-row prep: sm[k,:] = softmax(A[k,:]) (f64),
//           nK[k,:] = K[k,:] / max(||K[k,:]||, 1e-12)   (f64)
// ---------------------------------------------------------------------------
__global__ void prep_kernel(const float* __restrict__ A, const float* __restrict__ K,
                            double* __restrict__ sm, double* __restrict__ nK) {
    const int k = blockIdx.x;
    const int t = threadIdx.x;
    const int wave = t >> 6, lane = t & 63;
    __shared__ double red[4];

    double m = -1e300;
    for (int d = t; d < D_; d += 256) m = fmax(m, (double)A[k * D_ + d]);
    #pragma unroll
    for (int off = 32; off >= 1; off >>= 1) m = fmax(m, __shfl_xor(m, off));
    if (lane == 0) red[wave] = m;
    __syncthreads();
    m = fmax(fmax(red[0], red[1]), fmax(red[2], red[3]));
    __syncthreads();

    double s = 0.0;
    for (int d = t; d < D_; d += 256) s += exp((double)A[k * D_ + d] - m);
    #pragma unroll
    for (int off = 32; off >= 1; off >>= 1) s += __shfl_xor(s, off);
    if (lane == 0) red[wave] = s;
    __syncthreads();
    s = red[0] + red[1] + red[2] + red[3];
    __syncthreads();

    for (int d = t; d < D_; d += 256)
        sm[k * D_ + d] = exp((double)A[k * D_ + d] - m) / s;

    double ss = 0.0;
    for (int d = t; d < D_; d += 256) {
        double v = (double)K[k * D_ + d];
        ss += v * v;
    }
    #pragma unroll
    for (int off = 32; off >= 1; off >>= 1) ss += __shfl_xor(ss, off);
    if (lane == 0) red[wave] = ss;
    __syncthreads();
    ss = red[0] + red[1] + red[2] + red[3];
    const double n = fmax(sqrt(ss), 1e-12);

    for (int d = t; d < D_; d += 256)
        nK[k * D_ + d] = (double)K[k * D_ + d] / n;
}

// ---------------------------------------------------------------------------
// Kernel 2 (fused): score (blocks 0..1023, FULL parallelism — R7 lesson:
// score is latency-bound, 115 us at 1024 blocks, ~4x slower at 256 blocks;
// that, not "interference", sank R4/R5) + copy (blocks 1024.., the R7-proven
// 6.4 TB/s plain grid-stride float4 at 8192 blocks).
// Score blocks are dispatched first so they hold their resident slots; copy
// blocks stream in behind and hide the score entirely under HBM time.
// ---------------------------------------------------------------------------
__global__ void __launch_bounds__(256)
fused_kernel(const float* __restrict__ xq,
             const double* __restrict__ sm,
             const double* __restrict__ nK,
             const float* __restrict__ p,
             const f4_t* __restrict__ xb,
             float* __restrict__ out) {
    const int t = threadIdx.x;

    if (blockIdx.x >= B_) {
        // ---------------- copy role (R7-proven config) ----------------
        f4_t* __restrict__ dst = (f4_t*)(out + 2 * (size_t)EK_ELEMS);
        size_t i = (size_t)(blockIdx.x - B_) * 256 + t;
        const size_t stride = (size_t)COPY_BLOCKS * 256;
        for (; i < (size_t)XB_F4; i += stride)
            dst[i] = xb[i];
        return;
    }

    // ---------------- score role: one block per b-row ----------------
    __shared__ double s_xq[D_];
    __shared__ double s_aq[POOL_];
    __shared__ int    s_idx[TOPK_];
    const int b = blockIdx.x;
    const int wave = t >> 6, lane = t & 63;

    for (int d = t; d < D_; d += 256) s_xq[d] = (double)xq[b * D_ + d];
    __syncthreads();

    for (int k = wave; k < POOL_; k += 4) {
        const double* __restrict__ smk = sm + (size_t)k * D_;
        const double* __restrict__ nkk = nK + (size_t)k * D_;
        double dot = 0.0, sq = 0.0;
        for (int d = lane; d < D_; d += 64) {
            double v = s_xq[d] * smk[d];
            dot += v * nkk[d];
            sq  += v * v;
        }
        #pragma unroll
        for (int off = 32; off >= 1; off >>= 1) {
            dot += __shfl_xor(dot, off);
            sq  += __shfl_xor(sq, off);
        }
        if (lane == 0) s_aq[k] = dot / fmax(sqrt(sq), 1e-12);
    }
    __syncthreads();

    if (wave == 0) {
        // wave-parallel top-3; lane covers k=lane and k=lane+64;
        // tie -> lowest index (matches lax.top_k stability)
        double v0 = (lane < POOL_) ? s_aq[lane] : -1e300;
        double v1 = (lane + 64 < POOL_) ? s_aq[lane + 64] : -1e300;
        #pragma unroll
        for (int r = 0; r < TOPK_; ++r) {
            double v; int ki;
            if (v0 >= v1) { v = v0; ki = lane; }
            else          { v = v1; ki = lane + 64; }
            #pragma unroll
            for (int off = 32; off >= 1; off >>= 1) {
                double ov = __shfl_xor(v, off);
                int    oi = __shfl_xor(ki, off);
                if (ov > v || (ov == v && oi < ki)) { v = ov; ki = oi; }
            }
            if (lane == 0) s_idx[r] = ki;
            if (ki == lane)      v0 = -1e300;
            if (ki == lane + 64) v1 = -1e300;
        }
    }
    __syncthreads();
    const int i0 = s_idx[0], i1 = s_idx[1], i2 = s_idx[2];

    // gather: 8 prompt-rows x 192 float4 = 1536 units over 256 threads
    for (int w = t; w < PLEN_ * 192; w += 256) {
        const int j = w / 192, c = w % 192;
        const f4_t* __restrict__ q0 = (const f4_t*)(p + (size_t)(j * POOL_ + i0) * D_);
        const f4_t* __restrict__ q1 = (const f4_t*)(p + (size_t)(j * POOL_ + i1) * D_);
        const f4_t* __restrict__ q2 = (const f4_t*)(p + (size_t)(j * POOL_ + i2) * D_);
        f4_t v = q0[c] + q1[c] + q2[c];
        float* dst = (j < 4) ? out + ((size_t)b * 4 + j) * D_
                             : out + EK_ELEMS + ((size_t)b * 4 + (j - 4)) * D_;
        ((f4_t*)dst)[c] = v;
    }
}

extern "C" void kernel_launch(void* const* d_in, const int* in_sizes, int n_in,
                              void* d_out, int out_size, void* d_ws, size_t ws_size,
                              hipStream_t stream) {
    const float* x_querry = (const float*)d_in[0];   // (1024, 768)
    const float* x_block  = (const float*)d_in[1];   // (1024, 197, 768)
    const float* K        = (const float*)d_in[2];   // (100, 768)
    const float* A        = (const float*)d_in[3];   // (100, 768)
    const float* p        = (const float*)d_in[4];   // (8, 100, 768)
    // d_in[5] = l (unused)

    float* out = (float*)d_out;

    // workspace layout
    double* sm = (double*)d_ws;                 // 100*768 f64 = 614400 B
    double* nK = sm + (size_t)POOL_ * D_;       // 614400 B

    prep_kernel<<<POOL_, 256, 0, stream>>>(A, K, sm, nK);
    fused_kernel<<<NBLOCKS, 256, 0, stream>>>(x_querry, sm, nK, p,
                                              (const f4_t*)x_block, out);
}